// Round 14
// baseline (581.442 us; speedup 1.0000x reference)
//
#include <hip/hip_runtime.h>

#define NROWS 65536   // B*T
#define DIM   256
#define VCB   2048

typedef _Float16 f16;
typedef _Float16 f16x8 __attribute__((ext_vector_type(8)));
typedef float    f32x4 __attribute__((ext_vector_type(4)));

// ---------------- ws layout (bytes) ----------------
// [0,        262144)  idx        int[NROWS]
// [262144,   270336)  hist       uint[VCB]
// [270336,   272384)  loss_part  double[256]
// [272384,   280576)  enorm      float[VCB]
// [524288,  1572864)  e_hi       f16[VCB*DIM]
// [1572864, 2621440)  e_lo       f16[VCB*DIM]
// z_hi/z_lo (64 MB) live in d_out's z_q region as scratch until the gather pass.

__device__ __forceinline__ void async16(void* lds, const void* g) {
  __builtin_amdgcn_global_load_lds(
      (const __attribute__((address_space(1))) void*)g,
      (__attribute__((address_space(3))) void*)lds, 16, 0, 0);
}

// fp32 -> (f16 hi, f16 lo) split, 4 elems/thread/iter, grid-stride
__global__ __launch_bounds__(256) void convert_kernel(
    const float4* __restrict__ src, short4* __restrict__ dhi,
    short4* __restrict__ dlo, int n4) {
  int stride = gridDim.x * 256;
  for (int i = blockIdx.x * 256 + threadIdx.x; i < n4; i += stride) {
    float4 v = src[i];
    union { f16 h[4]; short4 s; } H, L;
    H.h[0] = (f16)v.x; H.h[1] = (f16)v.y; H.h[2] = (f16)v.z; H.h[3] = (f16)v.w;
    L.h[0] = (f16)(v.x - (float)H.h[0]);
    L.h[1] = (f16)(v.y - (float)H.h[1]);
    L.h[2] = (f16)(v.z - (float)H.h[2]);
    L.h[3] = (f16)(v.w - (float)H.h[3]);
    dhi[i] = H.s; dlo[i] = L.s;
  }
}

// zero hist + loss partials, compute ||e_j||^2 (one wave per codebook row), fp32
__global__ __launch_bounds__(256) void prep_kernel(
    const float* __restrict__ e, float* __restrict__ enorm,
    unsigned int* __restrict__ hist, double* __restrict__ loss_part) {
  int tid = threadIdx.x;
  int gt = blockIdx.x * 256 + tid;
  if (gt < VCB) hist[gt] = 0u;
  if (gt < 256) loss_part[gt] = 0.0;
  int wid  = gt >> 6;
  int lane = tid & 63;
  if (wid < VCB) {
    const float4* row = (const float4*)(e + (size_t)wid * DIM);
    float4 v = row[lane];
    float s = v.x*v.x + v.y*v.y + v.z*v.z + v.w*v.w;
    #pragma unroll
    for (int off = 32; off; off >>= 1) s += __shfl_xor(s, off);
    if (lane == 0) enorm[wid] = s;
  }
}

// Fused split-f16 MFMA distance GEMM + row argmin — barrier-free main loop,
// B stream register-double-buffered with NAMED ping/pong sets (static idx).
// A (z rows) LDS-resident (128KB, staged once). B loads directly from the
// L2-resident codebook with one-step register prefetch.
// amdgpu_waves_per_eu(1,2): r11-r13 proved __launch_bounds__' 2nd arg does
// NOT reach the VGPR budget (VGPR pinned at 128 = 4 waves/EU default ->
// ~80 spilled regs -> 272MB scratch). LDS already caps us at 2 waves/EU,
// so budget for 2 waves/EU (256 VGPR) explicitly via the clang attribute.
__global__ __launch_bounds__(512)
__attribute__((amdgpu_waves_per_eu(1, 2)))
void argmin_kernel(
    const f16* __restrict__ zh, const f16* __restrict__ zl,
    const f16* __restrict__ eh, const f16* __restrict__ el,
    const float* __restrict__ enorm,
    int* __restrict__ idx_out, unsigned int* __restrict__ hist) {
  // per kt tile: hi [0,4096) f16, lo [4096,8192) f16  ([128 rows][32 k])
  __shared__ f16 ldsA[8][8192];      // 128 KB, resident all kernel
  __shared__ float sxv[3][2][64];    // cross-wave merge scratch (3 KB)
  __shared__ int   sxi[3][2][64];

  const int tid  = threadIdx.x;
  const int wid  = tid >> 6;        // 0..7
  const int lane = tid & 63;
  const int wr   = wid >> 2;        // wave row 0..1 (64-row strip)
  const int wc   = wid & 3;         // wave col 0..3 (512-col span)
  const int lrow = lane & 15;       // frag row/col index
  const int lq   = lane >> 4;       // k-chunk 0..3
  const int rbase = blockIdx.x * 128;

  // prologue staging mapping: 512 threads cover one 8KB half-tile each issue
  const int srow = tid >> 2;        // 0..127
  const int scol = tid & 3;         // 16B chunk in row
  // XOR swizzle applied on GLOBAL source (LDS linear), mirrored on frag reads
  const int skoff = ((scol ^ ((srow >> 1) & 3)) << 3);

  // prologue: all 8 A k-tiles, one drain, then A is read-only forever
  #pragma unroll
  for (int kt = 0; kt < 8; ++kt) {
    size_t off = (size_t)(rbase + srow) * DIM + (kt << 5) + skoff;
    async16(&ldsA[kt][0]    + tid * 8, zh + off);
    async16(&ldsA[kt][4096] + tid * 8, zl + off);
  }
  __syncthreads();   // drains vmcnt(0): A resident

  float minv[4][4];
  int   mini[4][4];
  #pragma unroll
  for (int m = 0; m < 4; ++m)
    #pragma unroll
    for (int r = 0; r < 4; ++r) { minv[m][r] = 3.4e38f; mini[m][r] = 0; }

  const int cchunk = lq ^ ((lrow >> 1) & 3);
  const size_t lanecol = (size_t)(wc * 512 + lrow) * DIM + (lq << 3);

  // ---- named B ping/pong register sets (static indexing only) ----
  f16x8 bhP[4], blP[4], bhQ[4], blQ[4];

  // load step 0 (chunk 0, kt 0) into P
  #pragma unroll
  for (int n = 0; n < 4; ++n) {
    size_t boff = lanecol + (size_t)(n * 16) * DIM;
    bhP[n] = *(const f16x8*)(eh + boff);
    blP[n] = *(const f16x8*)(el + boff);
  }

  for (int chunk = 0; chunk < 8; ++chunk) {
    f32x4 acc[4][4];
    #pragma unroll
    for (int m = 0; m < 4; ++m)
      #pragma unroll
      for (int n = 0; n < 4; ++n) {
        f32x4 zz = {0.f, 0.f, 0.f, 0.f};
        acc[m][n] = zz;
      }

    for (int kt2 = 0; kt2 < 8; kt2 += 2) {
      const int s = chunk * 8 + kt2;

      // ======== half 1: consume P (step s), prefetch step s+1 into Q ======
      {
        const char* abase = (const char*)&ldsA[kt2][0];
        f16x8 ah[4], al[4];
        #pragma unroll
        for (int m = 0; m < 4; ++m) {
          int row = wr * 64 + m * 16 + lrow;
          int off = row * 64 + cchunk * 16;
          ah[m] = *(const f16x8*)(abase + off);
          al[m] = *(const f16x8*)(abase + 8192 + off);
        }
        {
          const int s1 = s + 1;                    // always < 64
          const int pc = s1 >> 3, pk = s1 & 7;
          #pragma unroll
          for (int n = 0; n < 4; ++n) {
            size_t boff = lanecol + (size_t)(pc * 64 + n * 16) * DIM + (pk << 5);
            bhQ[n] = *(const f16x8*)(eh + boff);
            blQ[n] = *(const f16x8*)(el + boff);
          }
        }
        __builtin_amdgcn_s_setprio(1);
        #pragma unroll
        for (int n = 0; n < 4; ++n)
          #pragma unroll
          for (int m = 0; m < 4; ++m) {
            acc[m][n] = __builtin_amdgcn_mfma_f32_16x16x32_f16(ah[m], bhP[n], acc[m][n], 0, 0, 0);
            acc[m][n] = __builtin_amdgcn_mfma_f32_16x16x32_f16(ah[m], blP[n], acc[m][n], 0, 0, 0);
            acc[m][n] = __builtin_amdgcn_mfma_f32_16x16x32_f16(al[m], bhP[n], acc[m][n], 0, 0, 0);
          }
        __builtin_amdgcn_s_setprio(0);
      }

      // ======== half 2: consume Q (step s+1), prefetch step s+2 into P ====
      {
        const char* abase = (const char*)&ldsA[kt2 + 1][0];
        f16x8 ah[4], al[4];
        #pragma unroll
        for (int m = 0; m < 4; ++m) {
          int row = wr * 64 + m * 16 + lrow;
          int off = row * 64 + cchunk * 16;
          ah[m] = *(const f16x8*)(abase + off);
          al[m] = *(const f16x8*)(abase + 8192 + off);
        }
        {
          int s2 = s + 2;
          if (s2 >= 64) s2 = 0;                    // tail: harmless dummy load
          const int pc = s2 >> 3, pk = s2 & 7;
          #pragma unroll
          for (int n = 0; n < 4; ++n) {
            size_t boff = lanecol + (size_t)(pc * 64 + n * 16) * DIM + (pk << 5);
            bhP[n] = *(const f16x8*)(eh + boff);
            blP[n] = *(const f16x8*)(el + boff);
          }
        }
        __builtin_amdgcn_s_setprio(1);
        #pragma unroll
        for (int n = 0; n < 4; ++n)
          #pragma unroll
          for (int m = 0; m < 4; ++m) {
            acc[m][n] = __builtin_amdgcn_mfma_f32_16x16x32_f16(ah[m], bhQ[n], acc[m][n], 0, 0, 0);
            acc[m][n] = __builtin_amdgcn_mfma_f32_16x16x32_f16(ah[m], blQ[n], acc[m][n], 0, 0, 0);
            acc[m][n] = __builtin_amdgcn_mfma_f32_16x16x32_f16(al[m], bhQ[n], acc[m][n], 0, 0, 0);
          }
        __builtin_amdgcn_s_setprio(0);
      }
    }

    // chunk epilogue: C/D layout col=lane&15, row=(lane>>4)*4+reg (m89/m91)
    const int cbase = wc * 512 + chunk * 64;
    #pragma unroll
    for (int n = 0; n < 4; ++n) {
      int j = cbase + n * 16 + lrow;
      float en = enorm[j];
      #pragma unroll
      for (int m = 0; m < 4; ++m)
        #pragma unroll
        for (int r = 0; r < 4; ++r) {
          float s = fmaf(-2.f, acc[m][n][r], en);
          if (s < minv[m][r]) { minv[m][r] = s; mini[m][r] = j; }
        }
    }
  }

  // reduce across the 16 lanes (lane bits 0..3) sharing each row; first-idx tie-break
  #pragma unroll
  for (int off = 1; off < 16; off <<= 1) {
    #pragma unroll
    for (int m = 0; m < 4; ++m)
      #pragma unroll
      for (int r = 0; r < 4; ++r) {
        float ov = __shfl_xor(minv[m][r], off);
        int   oi = __shfl_xor(mini[m][r], off);
        if (ov < minv[m][r] || (ov == minv[m][r] && oi < mini[m][r])) {
          minv[m][r] = ov; mini[m][r] = oi;
        }
      }
  }

  // cross-wave merge over the 4 wc groups (dedicated scratch, no aliasing)
  if (wc != 0 && lrow == 0) {
    #pragma unroll
    for (int m = 0; m < 4; ++m)
      #pragma unroll
      for (int r = 0; r < 4; ++r) {
        int li = m * 16 + lq * 4 + r;
        sxv[wc - 1][wr][li] = minv[m][r];
        sxi[wc - 1][wr][li] = mini[m][r];
      }
  }
  __syncthreads();
  if (wc == 0 && lrow == 0) {
    #pragma unroll
    for (int m = 0; m < 4; ++m)
      #pragma unroll
      for (int r = 0; r < 4; ++r) {
        int li = m * 16 + lq * 4 + r;
        float v  = minv[m][r];
        int   bi = mini[m][r];
        #pragma unroll
        for (int g = 0; g < 3; ++g) {
          float ov = sxv[g][wr][li];
          int   oi = sxi[g][wr][li];
          if (ov < v || (ov == v && oi < bi)) { v = ov; bi = oi; }
        }
        idx_out[rbase + wr * 64 + li] = bi;
        atomicAdd(&hist[bi], 1u);
      }
  }
}

// gather z_q = e[idx], write z_q_st + float indices, accumulate sum((z-z_q)^2)
__global__ __launch_bounds__(256) void gather_loss_kernel(
    const float* __restrict__ z, const float* __restrict__ e,
    const int* __restrict__ idx, float* __restrict__ zq_out,
    float* __restrict__ idxf_out, double* __restrict__ loss_part) {
  __shared__ float wsum[4];
  int tid  = threadIdx.x;
  int w    = tid >> 6;
  int lane = tid & 63;
  int n    = blockIdx.x * 4 + w;

  int ci = idx[n];
  const float4* zr = (const float4*)(z + (size_t)n  * DIM);
  const float4* er = (const float4*)(e + (size_t)ci * DIM);
  float4 zv = zr[lane];
  float4 ev = er[lane];
  ((float4*)(zq_out + (size_t)n * DIM))[lane] = ev;
  if (lane == 0) idxf_out[n] = (float)ci;

  float dx = zv.x - ev.x, dy = zv.y - ev.y, dz = zv.z - ev.z, dw = zv.w - ev.w;
  float s = dx*dx + dy*dy + dz*dz + dw*dw;
  #pragma unroll
  for (int off = 32; off; off >>= 1) s += __shfl_xor(s, off);
  if (lane == 0) wsum[w] = s;
  __syncthreads();
  if (tid == 0) {
    float bs = wsum[0] + wsum[1] + wsum[2] + wsum[3];
    atomicAdd(&loss_part[blockIdx.x & 255], (double)bs);
  }
}

__global__ __launch_bounds__(256) void finalize_kernel(
    const unsigned int* __restrict__ hist, const double* __restrict__ loss_part,
    float* __restrict__ out) {
  __shared__ double lsh[4];
  __shared__ float  hsh[4];
  __shared__ float  denom_sh;
  int tid = threadIdx.x, lane = tid & 63, w = tid >> 6;

  float hs = 0.f;
  for (int j = tid; j < VCB; j += 256) hs += (float)hist[j];
  double ls = loss_part[tid];
  #pragma unroll
  for (int off = 32; off; off >>= 1) {
    hs += __shfl_xor(hs, off);
    ls += __shfl_xor(ls, off);
  }
  if (lane == 0) { lsh[w] = ls; hsh[w] = hs; }
  __syncthreads();
  if (tid == 0) {
    double lt = lsh[0] + lsh[1] + lsh[2] + lsh[3];
    float  ht = hsh[0] + hsh[1] + hsh[2] + hsh[3];
    out[0] = (float)(lt / (double)((size_t)NROWS * DIM));
    denom_sh = ht + 1e-8f;
  }
  __syncthreads();
  float denom = denom_sh;
  float* prob = out + 1 + (size_t)NROWS * DIM + NROWS;
  for (int j = tid; j < VCB; j += 256) prob[j] = (float)hist[j] / denom;
}

extern "C" void kernel_launch(void* const* d_in, const int* in_sizes, int n_in,
                              void* d_out, int out_size, void* d_ws, size_t ws_size,
                              hipStream_t stream) {
  (void)in_sizes; (void)n_in; (void)out_size; (void)ws_size;
  const float* z = (const float*)d_in[0];
  const float* e = (const float*)d_in[1];
  float* out = (float*)d_out;
  char*  ws  = (char*)d_ws;

  int*          idx       = (int*)ws;
  unsigned int* hist      = (unsigned int*)(ws + 262144);
  double*       loss_part = (double*)(ws + 270336);
  float*        enorm     = (float*)(ws + 272384);
  f16*          e_hi      = (f16*)(ws + 524288);
  f16*          e_lo      = (f16*)(ws + 1572864);

  // z split lives in d_out's z_q region (scratch until gather pass).
  f16* z_hi = (f16*)(out + 4);
  f16* z_lo = z_hi + (size_t)NROWS * DIM;

  float* out_zq  = out + 1;
  float* out_idx = out + 1 + (size_t)NROWS * DIM;

  convert_kernel<<<1024, 256, 0, stream>>>(
      (const float4*)z, (short4*)z_hi, (short4*)z_lo, NROWS * DIM / 4);
  convert_kernel<<<128, 256, 0, stream>>>(
      (const float4*)e, (short4*)e_hi, (short4*)e_lo, VCB * DIM / 4);
  prep_kernel<<<512, 256, 0, stream>>>(e, enorm, hist, loss_part);
  argmin_kernel<<<NROWS / 128, 512, 0, stream>>>(
      z_hi, z_lo, e_hi, e_lo, enorm, idx, hist);
  gather_loss_kernel<<<NROWS / 4, 256, 0, stream>>>(
      z, e, idx, out_zq, out_idx, loss_part);
  finalize_kernel<<<1, 256, 0, stream>>>(hist, loss_part, out);
}

// Round 15
// 250.796 us; speedup vs baseline: 2.3184x; 2.3184x over previous
//
#include <hip/hip_runtime.h>

#define NROWS 65536   // B*T
#define DIM   256
#define VCB   2048

typedef _Float16 f16;
typedef _Float16 f16x8 __attribute__((ext_vector_type(8)));
typedef float    f32x4 __attribute__((ext_vector_type(4)));

// ---------------- ws layout (bytes) ----------------
// [0,        262144)  idx        int[NROWS]
// [262144,   270336)  hist       uint[VCB]
// [270336,   272384)  loss_part  double[256]
// [272384,   280576)  enorm      float[VCB]
// [524288,  1572864)  e_hi       f16[VCB*DIM]
// [1572864, 2621440)  e_lo       f16[VCB*DIM]

__device__ __forceinline__ void async16(void* lds, const void* g) {
  __builtin_amdgcn_global_load_lds(
      (const __attribute__((address_space(1))) void*)g,
      (__attribute__((address_space(3))) void*)lds, 16, 0, 0);
}

// fp32 -> (f16 hi, f16 lo) split — used for the 2MB codebook only now
__global__ __launch_bounds__(256) void convert_kernel(
    const float4* __restrict__ src, short4* __restrict__ dhi,
    short4* __restrict__ dlo, int n4) {
  int stride = gridDim.x * 256;
  for (int i = blockIdx.x * 256 + threadIdx.x; i < n4; i += stride) {
    float4 v = src[i];
    union { f16 h[4]; short4 s; } H, L;
    H.h[0] = (f16)v.x; H.h[1] = (f16)v.y; H.h[2] = (f16)v.z; H.h[3] = (f16)v.w;
    L.h[0] = (f16)(v.x - (float)H.h[0]);
    L.h[1] = (f16)(v.y - (float)H.h[1]);
    L.h[2] = (f16)(v.z - (float)H.h[2]);
    L.h[3] = (f16)(v.w - (float)H.h[3]);
    dhi[i] = H.s; dlo[i] = L.s;
  }
}

// zero hist + loss partials, compute ||e_j||^2 (one wave per codebook row), fp32
__global__ __launch_bounds__(256) void prep_kernel(
    const float* __restrict__ e, float* __restrict__ enorm,
    unsigned int* __restrict__ hist, double* __restrict__ loss_part) {
  int tid = threadIdx.x;
  int gt = blockIdx.x * 256 + tid;
  if (gt < VCB) hist[gt] = 0u;
  if (gt < 256) loss_part[gt] = 0.0;
  int wid  = gt >> 6;
  int lane = tid & 63;
  if (wid < VCB) {
    const float4* row = (const float4*)(e + (size_t)wid * DIM);
    float4 v = row[lane];
    float s = v.x*v.x + v.y*v.y + v.z*v.z + v.w*v.w;
    #pragma unroll
    for (int off = 32; off; off >>= 1) s += __shfl_xor(s, off);
    if (lane == 0) enorm[wid] = s;
  }
}

// Fused split-f16 MFMA distance GEMM + row argmin (r9 main loop, verified).
// NEW: (a) z conversion fused into the prologue — reg-stage fp32 z, split
// hi/lo in registers, swizzled ds_write into the resident A tiles (no more
// separate convert pass or d_out scratch); (b) commitment loss computed here:
// loss = (sum(minv) + sum(z^2)) / (N*D), since minv = d_min - ||z||^2.
// A (z) LDS-resident 128KB; B staged 16KB tiles, counted vmcnt(2), 2 barriers
// per phase. 512 threads = 8 waves (2 wr x 4 wc), superstep 512 cols.
__global__ __launch_bounds__(512) void argmin_kernel(
    const float* __restrict__ z,
    const f16* __restrict__ eh, const f16* __restrict__ el,
    const float* __restrict__ enorm,
    int* __restrict__ idx_out, unsigned int* __restrict__ hist,
    double* __restrict__ loss_part) {
  // per kt tile: hi [0,8192)B, lo [8192,16384)B  ([128 rows][32 f16] each)
  __shared__ f16 ldsA[8][8192];   // 128 KB, resident all kernel
  __shared__ f16 ldsB[2][8192];   // 32 KB double buffer (merge aliases later)

  const int tid  = threadIdx.x;
  const int wid  = tid >> 6;        // 0..7
  const int lane = tid & 63;
  const int wr   = wid >> 2;        // wave row 0..1 (64-row strip)
  const int wc   = wid & 3;         // wave col 0..3 (32-col strip in 128-col half)
  const int lrow = lane & 15;       // frag row/col index
  const int lq   = lane >> 4;       // k-chunk 0..3
  const int rbase = blockIdx.x * 128;

  // B staging mapping: 512 threads cover one 8KB half-tile (1 load each)
  const int srow = tid >> 2;        // 0..127
  const int scol = tid & 3;         // 16B chunk in row
  const int skoff = ((scol ^ ((srow >> 1) & 3)) << 3);  // pre-swizzled source

  auto stageB = [&](int b, int vcol, int kt) {   // 2 loads/thread
    size_t off = (size_t)(vcol + srow) * DIM + (kt << 5) + skoff;
    async16(&ldsB[b][0]    + tid * 8, eh + off);
    async16(&ldsB[b][4096] + tid * 8, el + off);
  };

  // ---- prologue: reg-stage z fp32 -> hi/lo split -> swizzled ds_write ----
  // thread covers row=tid>>2, cols [q*64,(q+1)*64), q=tid&3. Also sums z^2.
  {
    const int row = tid >> 2;
    const int q   = tid & 3;
    const float* zrow = z + (size_t)(rbase + row) * DIM + q * 64;
    const int sw = (row >> 1) & 3;
    float zs = 0.f;
    #pragma unroll
    for (int f = 0; f < 16; ++f) {
      float4 v = *(const float4*)(zrow + f * 4);
      int col4   = q * 64 + f * 4;
      int kt     = col4 >> 5;
      int ko     = col4 & 31;                       // f16 idx within kt-row
      int chunk  = ko >> 3;                         // 16B chunk 0..3
      int within = (ko & 7) * 2;                    // 0 or 8
      int addr = kt * 16384 + row * 64 + ((chunk ^ sw) << 4) + within;
      union { f16 h[4]; short4 s4; } H, L;
      H.h[0] = (f16)v.x; H.h[1] = (f16)v.y; H.h[2] = (f16)v.z; H.h[3] = (f16)v.w;
      L.h[0] = (f16)(v.x - (float)H.h[0]);
      L.h[1] = (f16)(v.y - (float)H.h[1]);
      L.h[2] = (f16)(v.z - (float)H.h[2]);
      L.h[3] = (f16)(v.w - (float)H.h[3]);
      *(short4*)((char*)ldsA + addr)        = H.s4;
      *(short4*)((char*)ldsA + addr + 8192) = L.s4;
      zs += v.x*v.x + v.y*v.y + v.z*v.z + v.w*v.w;
    }
    #pragma unroll
    for (int off = 32; off; off >>= 1) zs += __shfl_xor(zs, off);
    if (lane == 0) atomicAdd(&loss_part[blockIdx.x & 255], (double)zs);
  }
  stageB(0, 0, 0);
  asm volatile("s_waitcnt vmcnt(0)" ::: "memory");
  __syncthreads();   // also drains lgkmcnt: A tiles + B(0) resident

  float minv[4][4];
  int   mini[4][4];
  #pragma unroll
  for (int m = 0; m < 4; ++m)
    #pragma unroll
    for (int r = 0; r < 4; ++r) { minv[m][r] = 3.4e38f; mini[m][r] = 0; }

  const int cchunk = lq ^ ((lrow >> 1) & 3);

  int pb = 0;
  for (int ss = 0; ss < 4; ++ss) {
    const int vt = ss << 9;            // superstep base col (512 cols)
    f32x4 acc[4][4][2];                // [half][m][n]
    #pragma unroll
    for (int h = 0; h < 4; ++h)
      #pragma unroll
      for (int m = 0; m < 4; ++m)
        #pragma unroll
        for (int n = 0; n < 2; ++n) {
          f32x4 zz = {0.f, 0.f, 0.f, 0.f};
          acc[h][m][n] = zz;
        }

    f16x8 ah[4], al[4];
    for (int kt = 0; kt < 8; ++kt) {
      #pragma unroll
      for (int h = 0; h < 4; ++h) {
        // stage next phase's B tile into the other buffer
        bool last = (ss == 3) && (kt == 7) && (h == 3);
        if (!last) {
          int nh = h + 1, nkt = kt, nss = ss;
          if (nh == 4) { nh = 0; ++nkt; if (nkt == 8) { nkt = 0; ++nss; } }
          stageB(pb ^ 1, (nss << 9) + (nh << 7), nkt);
          asm volatile("s_waitcnt vmcnt(2)" ::: "memory");
        } else {
          asm volatile("s_waitcnt vmcnt(0)" ::: "memory");
        }
        asm volatile("s_barrier" ::: "memory");
        __builtin_amdgcn_sched_barrier(0);

        if (h == 0) {   // A frags for this kt (reused for all 4 halves)
          const char* abase = (const char*)&ldsA[kt][0];
          #pragma unroll
          for (int m = 0; m < 4; ++m) {
            int row = wr * 64 + m * 16 + lrow;
            int off = row * 64 + cchunk * 16;
            ah[m] = *(const f16x8*)(abase + off);
            al[m] = *(const f16x8*)(abase + 8192 + off);
          }
        }
        const char* bbase = (const char*)&ldsB[0][0] + pb * 16384;
        __builtin_amdgcn_s_setprio(1);
        #pragma unroll
        for (int n = 0; n < 2; ++n) {
          int col = wc * 32 + n * 16 + lrow;
          int off = col * 64 + cchunk * 16;
          f16x8 bh = *(const f16x8*)(bbase + off);
          f16x8 bl = *(const f16x8*)(bbase + 8192 + off);
          #pragma unroll
          for (int m = 0; m < 4; ++m) {
            acc[h][m][n] = __builtin_amdgcn_mfma_f32_16x16x32_f16(ah[m], bh, acc[h][m][n], 0, 0, 0);
            acc[h][m][n] = __builtin_amdgcn_mfma_f32_16x16x32_f16(ah[m], bl, acc[h][m][n], 0, 0, 0);
            acc[h][m][n] = __builtin_amdgcn_mfma_f32_16x16x32_f16(al[m], bh, acc[h][m][n], 0, 0, 0);
          }
        }
        __builtin_amdgcn_s_setprio(0);
        __builtin_amdgcn_sched_barrier(0);
        asm volatile("s_barrier" ::: "memory");
        pb ^= 1;
      }
    }

    // epilogue: C/D layout col=lane&15, row=(lane>>4)*4+reg (m89/m91)
    #pragma unroll
    for (int h = 0; h < 4; ++h)
      #pragma unroll
      for (int n = 0; n < 2; ++n) {
        int j = vt + (h << 7) + wc * 32 + n * 16 + lrow;
        float en = enorm[j];
        #pragma unroll
        for (int m = 0; m < 4; ++m)
          #pragma unroll
          for (int r = 0; r < 4; ++r) {
            float s = fmaf(-2.f, acc[h][m][n][r], en);
            if (s < minv[m][r]) { minv[m][r] = s; mini[m][r] = j; }
          }
      }
  }

  // reduce across the 16 lanes (lane bits 0..3) sharing each row; first-idx tie-break
  #pragma unroll
  for (int off = 1; off < 16; off <<= 1) {
    #pragma unroll
    for (int m = 0; m < 4; ++m)
      #pragma unroll
      for (int r = 0; r < 4; ++r) {
        float ov = __shfl_xor(minv[m][r], off);
        int   oi = __shfl_xor(mini[m][r], off);
        if (ov < minv[m][r] || (ov == minv[m][r] && oi < mini[m][r])) {
          minv[m][r] = ov; mini[m][r] = oi;
        }
      }
  }

  // cross-wave merge over the 4 wc groups; merge scratch ALIASES ldsB
  __syncthreads();
  float* sxv = (float*)&ldsB[0][0];          // [3][2][64]
  int*   sxi = (int*)(sxv + 3 * 2 * 64);
  if (wc != 0 && lrow == 0) {
    #pragma unroll
    for (int m = 0; m < 4; ++m)
      #pragma unroll
      for (int r = 0; r < 4; ++r) {
        int li = m * 16 + lq * 4 + r;
        int ix = ((wc - 1) * 2 + wr) * 64 + li;
        sxv[ix] = minv[m][r];
        sxi[ix] = mini[m][r];
      }
  }
  __syncthreads();
  if (wc == 0 && lrow == 0) {
    float lsum = 0.f;
    #pragma unroll
    for (int m = 0; m < 4; ++m)
      #pragma unroll
      for (int r = 0; r < 4; ++r) {
        int li = m * 16 + lq * 4 + r;
        float v  = minv[m][r];
        int   bi = mini[m][r];
        #pragma unroll
        for (int g = 0; g < 3; ++g) {
          int ix = (g * 2 + wr) * 64 + li;
          float ov = sxv[ix];
          int   oi = sxi[ix];
          if (ov < v || (ov == v && oi < bi)) { v = ov; bi = oi; }
        }
        idx_out[rbase + wr * 64 + li] = bi;
        atomicAdd(&hist[bi], 1u);
        lsum += v;                        // v = d_min - ||z_row||^2
      }
    lsum += __shfl_xor(lsum, 16);
    lsum += __shfl_xor(lsum, 32);
    if (lane == 0) atomicAdd(&loss_part[blockIdx.x & 255], (double)lsum);
  }
}

// gather z_q = e[idx] (exact fp32), write z_q_st + float indices
__global__ __launch_bounds__(256) void gather_kernel(
    const float* __restrict__ e, const int* __restrict__ idx,
    float* __restrict__ zq_out, float* __restrict__ idxf_out) {
  int tid  = threadIdx.x;
  int w    = tid >> 6;
  int lane = tid & 63;
  int n    = blockIdx.x * 4 + w;

  int ci = idx[n];
  const float4* er = (const float4*)(e + (size_t)ci * DIM);
  ((float4*)(zq_out + (size_t)n * DIM))[lane] = er[lane];
  if (lane == 0) idxf_out[n] = (float)ci;
}

__global__ __launch_bounds__(256) void finalize_kernel(
    const unsigned int* __restrict__ hist, const double* __restrict__ loss_part,
    float* __restrict__ out) {
  __shared__ double lsh[4];
  __shared__ float  hsh[4];
  __shared__ float  denom_sh;
  int tid = threadIdx.x, lane = tid & 63, w = tid >> 6;

  float hs = 0.f;
  for (int j = tid; j < VCB; j += 256) hs += (float)hist[j];
  double ls = loss_part[tid];
  #pragma unroll
  for (int off = 32; off; off >>= 1) {
    hs += __shfl_xor(hs, off);
    ls += __shfl_xor(ls, off);
  }
  if (lane == 0) { lsh[w] = ls; hsh[w] = hs; }
  __syncthreads();
  if (tid == 0) {
    double lt = lsh[0] + lsh[1] + lsh[2] + lsh[3];
    float  ht = hsh[0] + hsh[1] + hsh[2] + hsh[3];
    out[0] = (float)(lt / (double)((size_t)NROWS * DIM));
    denom_sh = ht + 1e-8f;
  }
  __syncthreads();
  float denom = denom_sh;
  float* prob = out + 1 + (size_t)NROWS * DIM + NROWS;
  for (int j = tid; j < VCB; j += 256) prob[j] = (float)hist[j] / denom;
}

extern "C" void kernel_launch(void* const* d_in, const int* in_sizes, int n_in,
                              void* d_out, int out_size, void* d_ws, size_t ws_size,
                              hipStream_t stream) {
  (void)in_sizes; (void)n_in; (void)out_size; (void)ws_size;
  const float* z = (const float*)d_in[0];
  const float* e = (const float*)d_in[1];
  float* out = (float*)d_out;
  char*  ws  = (char*)d_ws;

  int*          idx       = (int*)ws;
  unsigned int* hist      = (unsigned int*)(ws + 262144);
  double*       loss_part = (double*)(ws + 270336);
  float*        enorm     = (float*)(ws + 272384);
  f16*          e_hi      = (f16*)(ws + 524288);
  f16*          e_lo      = (f16*)(ws + 1572864);

  float* out_zq  = out + 1;
  float* out_idx = out + 1 + (size_t)NROWS * DIM;

  convert_kernel<<<128, 256, 0, stream>>>(
      (const float4*)e, (short4*)e_hi, (short4*)e_lo, VCB * DIM / 4);
  prep_kernel<<<512, 256, 0, stream>>>(e, enorm, hist, loss_part);
  argmin_kernel<<<NROWS / 128, 512, 0, stream>>>(
      z, e_hi, e_lo, enorm, idx, hist, loss_part);
  gather_kernel<<<NROWS / 4, 256, 0, stream>>>(e, idx, out_zq, out_idx);
  finalize_kernel<<<1, 256, 0, stream>>>(hist, loss_part, out);
}